// Round 13
// baseline (169.773 us; speedup 1.0000x reference)
//
#include <hip/hip_runtime.h>
#include <hip/hip_fp16.h>

#define DD 300
#define SS 512
#define VV 50000

// Workspace layout (float index):
#define CK       0
#define CQS      1
#define BU       2        // B·u
#define BW1      3        // B·w1
#define C3A      4        // (Wd@Wx)@B (3)
#define C3B      8        // (Wd@Wx^2)@B (3)
#define C3C      12       // Wd@B + bd (3)
#define U_OFF    16       // u_emb = Wk^T wk (300)
#define UQ_OFF   320      // uq = Wq^T wq (300)
#define UQWX_OFF 640      // u  = Wx^T uq (300)     [atomic, plvl2]
#define W1_OFF   960      // w1 = X2^T uq (300)     [atomic, plvl2]
#define W2_OFF   1280     // w2 = X2^T u (300)      [atomic, plvl3]
#define P1_OFF   1600     // p1 = C^T u             [atomic, plvl3]
#define P2_OFF   1920     // p2 = C^T w1            [atomic, plvl3]
#define D0_OFF   2240     // D0_r = Wx^T a2_r (3x300) [atomic, plvl3]
#define D1_OFF   3200     // D1_r = C^T a2_r        [atomic, plvl3]
#define D2_OFF   4160     // D2_r = C^T a1_r        [atomic, plvl2]
#define D3_OFF   5120     // D3_r = C^T d_r         [atomic, plvl2]
#define BCB_OFF  6080     // B = Wp@bk + bp + bx (300)
#define A1_OFF   6400     // a1_r = Wx^T d_r (3x300)
#define A2_OFF   7360     // a2_r = X2^T d_r (3x300) [atomic, plvl2]
#define TAB_OFF  16384    // tab[v][12]
#define X2_OFF   700000   // Wx@Wx row-major (90000)
#define C_OFF    800000   // Wp@Wk row-major (90000)

#define FMA4(acc, s, v) { acc.x += (s)*(v).x; acc.y += (s)*(v).y; \
                          acc.z += (s)*(v).z; acc.w += (s)*(v).w; }

__device__ __forceinline__ float fast_exp_tanh(float z) {
    const float t = __expf(2.0f * z);
    return __expf(1.0f - 2.0f / (t + 1.0f));
}

__device__ __forceinline__ float wred(float v) {
    #pragma unroll
    for (int off = 32; off; off >>= 1) v += __shfl_xor(v, off);
    return v;
}

// ---------------------------------------------------------------------------
// vcomb16: sOut[j] = sum_i sIn[i]*M[i][j], 1024 threads / 16 waves.
// ---------------------------------------------------------------------------
__device__ __forceinline__ void vcomb16(
    const float* __restrict__ M, const float* __restrict__ sIn,
    float* __restrict__ sOut, float* __restrict__ buf,
    const int tid, const int wv, const int lane)
{
    float4 a0{0,0,0,0}, a1{0,0,0,0};
    for (int e = wv; e < DD; e += 16) {
        const float4* kr = (const float4*)(M + (size_t)e * DD);
        const float s = sIn[e];
        FMA4(a0, s, kr[lane]);
        if (lane < 11) { const float4 k1 = kr[64 + lane]; FMA4(a1, s, k1); }
    }
    float4* pr = (float4*)(buf + wv * 304);
    pr[lane] = a0;
    if (lane < 11) pr[64 + lane] = a1;
    __syncthreads();
    if (tid < DD) {
        float s = 0.f;
        #pragma unroll
        for (int w = 0; w < 16; ++w) s += buf[w * 304 + tid];
        sOut[tid] = s;
    }
    __syncthreads();
}

// ---------------------------------------------------------------------------
// rowcomb3_16: sOut[r][:] = sum_i sIn[r][i]*M[i][:], 16 waves.
// ---------------------------------------------------------------------------
__device__ __forceinline__ void rowcomb3_16(
    const float* __restrict__ M, const float (*sIn)[304], float (*sOut)[304],
    float* __restrict__ buf, const int tid, const int wv, const int lane)
{
    float4 a00{0,0,0,0}, a01{0,0,0,0}, a10{0,0,0,0},
           a11{0,0,0,0}, a20{0,0,0,0}, a21{0,0,0,0};
    for (int e = wv; e < DD; e += 16) {
        const float4* kr = (const float4*)(M + (size_t)e * DD);
        const float4 k0 = kr[lane];
        const float p0 = sIn[0][e], p1 = sIn[1][e], p2 = sIn[2][e];
        FMA4(a00, p0, k0); FMA4(a10, p1, k0); FMA4(a20, p2, k0);
        if (lane < 11) {
            const float4 k1 = kr[64 + lane];
            FMA4(a01, p0, k1); FMA4(a11, p1, k1); FMA4(a21, p2, k1);
        }
    }
    float4* p0r = (float4*)(buf + (wv * 3 + 0) * 304);
    float4* p1r = (float4*)(buf + (wv * 3 + 1) * 304);
    float4* p2r = (float4*)(buf + (wv * 3 + 2) * 304);
    p0r[lane] = a00; p1r[lane] = a10; p2r[lane] = a20;
    if (lane < 11) { p0r[64+lane] = a01; p1r[64+lane] = a11; p2r[64+lane] = a21; }
    __syncthreads();
    if (tid < DD) {
        #pragma unroll
        for (int r = 0; r < 3; ++r) {
            float s = 0.f;
            for (int w = 0; w < 16; ++w) s += buf[(w * 3 + r) * 304 + tid];
            sOut[r][tid] = s;
        }
    }
    __syncthreads();
}

// ---------------------------------------------------------------------------
// pre1: 205 blocks x 1024.
//   0..99  : C = Wp@Wk rows.  100..199: X2 = Wx@Wx rows.
//   200: ue = Wk^T wk ; ck.   201: uq = Wq^T wq ; cqs.
//   202: B = Wp@bk+bp+bx ; c3c_r = Wd_r·B + bd_r.
//   203: a1_r = Wx^T Wd_r.    204: zero all atomic targets of plvl2/plvl3.
// ---------------------------------------------------------------------------
__global__ __launch_bounds__(1024) void pre1(
    const float* __restrict__ Wk, const float* __restrict__ bk,
    const float* __restrict__ Wq, const float* __restrict__ bq,
    const float* __restrict__ w_mlp,
    const float* __restrict__ Wp, const float* __restrict__ bp,
    const float* __restrict__ Wx, const float* __restrict__ bx,
    const float* __restrict__ Wd, const float* __restrict__ bd,
    float* __restrict__ ws)
{
    const int blk  = blockIdx.x;
    const int tid  = threadIdx.x;
    const int wv   = tid >> 6;
    const int lane = tid & 63;
    __shared__ __align__(16) float buf[16 * 304 * 3];
    __shared__ __align__(16) float v0[304], v1[304], vB[304];
    __shared__ __align__(16) float m0[3][304], mW[3][304];
    __shared__ float red[16];

    if (blk < 200) {
        const bool isC = (blk < 100);
        const int i0 = (isC ? blk : blk - 100) * 3;
        const float* Arows = isC ? Wp : Wx;
        const float* Mrows = isC ? Wk : Wx;
        const int outoff = isC ? C_OFF : X2_OFF;

        for (int r = tid; r < 3 * DD; r += 1024)
            mW[r / DD][r % DD] = Arows[i0 * DD + r];
        __syncthreads();

        float4 a00{0,0,0,0}, a01{0,0,0,0}, a10{0,0,0,0},
               a11{0,0,0,0}, a20{0,0,0,0}, a21{0,0,0,0};
        for (int e = wv; e < DD; e += 16) {
            const float4* kr = (const float4*)(Mrows + (size_t)e * DD);
            const float4 k0 = kr[lane];
            const float p0 = mW[0][e], p1 = mW[1][e], p2 = mW[2][e];
            FMA4(a00, p0, k0); FMA4(a10, p1, k0); FMA4(a20, p2, k0);
            if (lane < 11) {
                const float4 k1 = kr[64 + lane];
                FMA4(a01, p0, k1); FMA4(a11, p1, k1); FMA4(a21, p2, k1);
            }
        }
        float4* p0r = (float4*)(buf + (wv * 3 + 0) * 304);
        float4* p1r = (float4*)(buf + (wv * 3 + 1) * 304);
        float4* p2r = (float4*)(buf + (wv * 3 + 2) * 304);
        p0r[lane] = a00; p1r[lane] = a10; p2r[lane] = a20;
        if (lane < 11) { p0r[64+lane] = a01; p1r[64+lane] = a11; p2r[64+lane] = a21; }
        __syncthreads();
        if (tid < DD) {
            #pragma unroll
            for (int r = 0; r < 3; ++r) {
                float s = 0.f;
                for (int w = 0; w < 16; ++w) s += buf[(w * 3 + r) * 304 + tid];
                ws[outoff + (size_t)(i0 + r) * DD + tid] = s;
            }
        }
        return;
    }

    if (blk == 200) {                       // ue + ck
        if (tid < DD) v0[tid] = w_mlp[tid];
        __syncthreads();
        vcomb16(Wk, v0, v1, buf, tid, wv, lane);
        if (tid < DD) ws[U_OFF + tid] = v1[tid];
        float p = (tid < DD) ? v0[tid] * bk[tid] : 0.f;
        p = wred(p);
        if (lane == 0) red[wv] = p;
        __syncthreads();
        if (tid == 0) {
            float s = 0.f;
            for (int w = 0; w < 16; ++w) s += red[w];
            ws[CK] = s;
        }
        return;
    }

    if (blk == 201) {                       // uq + cqs
        if (tid < DD) v0[tid] = w_mlp[DD + tid];
        __syncthreads();
        vcomb16(Wq, v0, v1, buf, tid, wv, lane);
        if (tid < DD) ws[UQ_OFF + tid] = v1[tid];
        float p = (tid < DD) ? (v0[tid] * bq[tid] + v1[tid] * bx[tid]) : 0.f;
        p = wred(p);
        if (lane == 0) red[wv] = p;
        __syncthreads();
        if (tid == 0) {
            float s = 0.f;
            for (int w = 0; w < 16; ++w) s += red[w];
            ws[CQS] = s;
        }
        return;
    }

    if (blk == 202) {                       // B + c3c
        if (tid < DD) v0[tid] = bk[tid];
        __syncthreads();
        {
            const float4* b4 = (const float4*)v0;
            const float4 k0 = b4[lane];
            const float4 k1 = (lane < 11) ? b4[64 + lane] : float4{0, 0, 0, 0};
            for (int i2 = wv; i2 < DD; i2 += 16) {
                const float4* wr = (const float4*)(Wp + (size_t)i2 * DD);
                const float4 w0 = wr[lane];
                float a = w0.x * k0.x + w0.y * k0.y + w0.z * k0.z + w0.w * k0.w;
                if (lane < 11) {
                    const float4 w1 = wr[64 + lane];
                    a += w1.x * k1.x + w1.y * k1.y + w1.z * k1.z + w1.w * k1.w;
                }
                a = wred(a);
                if (lane == 0) { vB[i2] = a + bp[i2] + bx[i2]; }
            }
        }
        __syncthreads();
        if (tid < DD) ws[BCB_OFF + tid] = vB[tid];
        if (wv < 3) {                       // c3c_r = Wd_r·B + bd_r
            float a = 0.f;
            for (int j = lane; j < DD; j += 64) a += Wd[wv * DD + j] * vB[j];
            a = wred(a);
            if (lane == 0) ws[C3C + wv] = a + bd[wv];
        }
        return;
    }

    if (blk == 203) {                       // a1_r = Wd_r @ Wx
        for (int r = tid; r < 3 * DD; r += 1024) mW[r / DD][r % DD] = Wd[r];
        __syncthreads();
        rowcomb3_16(Wx, mW, m0, buf, tid, wv, lane);
        for (int r = tid; r < 3 * DD; r += 1024)
            ws[A1_OFF + (r / DD) * DD + (r % DD)] = m0[r / DD][r % DD];
        return;
    }

    {   // blk 204: zero atomic targets
#define ZZ(off, len) for (int j = tid; j < (len); j += 1024) ws[(off) + j] = 0.f;
        ZZ(UQWX_OFF, 300) ZZ(W1_OFF, 300) ZZ(W2_OFF, 300)
        ZZ(P1_OFF, 300)   ZZ(P2_OFF, 300)
        ZZ(A2_OFF, 900)   ZZ(D0_OFF, 900) ZZ(D1_OFF, 900)
        ZZ(D2_OFF, 900)   ZZ(D3_OFF, 900)
#undef ZZ
    }
}

// ---------------------------------------------------------------------------
// plvl: level 2/3 products, each split 16-way over the reduction dim with
// atomicAdd accumulation (targets zeroed in pre1 blk204). 256 threads.
// Last block computes the level's scalars.
// ---------------------------------------------------------------------------
__global__ __launch_bounds__(256) void plvl(
    const float* __restrict__ Wx, const float* __restrict__ Wd,
    float* __restrict__ ws, const int lvl)
{
    const int S2[11] = {UQ_OFF, UQ_OFF, -1, -2, -3, -1, -2, -3,
                        A1_OFF, A1_OFF + 300, A1_OFF + 600};
    const int M2[11] = {0, 1, 1, 1, 1, 2, 2, 2, 2, 2, 2};
    const int T2[11] = {UQWX_OFF, W1_OFF, A2_OFF, A2_OFF + 300, A2_OFF + 600,
                        D3_OFF, D3_OFF + 300, D3_OFF + 600,
                        D2_OFF, D2_OFF + 300, D2_OFF + 600};
    const int S3[9]  = {UQWX_OFF, UQWX_OFF, W1_OFF,
                        A2_OFF, A2_OFF + 300, A2_OFF + 600,
                        A2_OFF, A2_OFF + 300, A2_OFF + 600};
    const int M3[9]  = {1, 2, 2, 2, 2, 2, 0, 0, 0};
    const int T3[9]  = {W2_OFF, P1_OFF, P2_OFF,
                        D1_OFF, D1_OFF + 300, D1_OFF + 600,
                        D0_OFF, D0_OFF + 300, D0_OFF + 600};
    const int nt = (lvl == 2) ? 11 : 9;

    const int tid  = threadIdx.x;
    const int lane = tid & 63;
    const int wv   = tid >> 6;
    const int bi   = blockIdx.x;

    __shared__ __align__(16) float sv[304];
    __shared__ __align__(16) float buf[4 * 304];

    if (bi >= nt * 16) {                    // scalar block
        if (lvl == 2) {
            if (wv < 3) {                   // c3a_r = a1_r·B
                float a = 0.f;
                for (int j = lane; j < DD; j += 64)
                    a += ws[A1_OFF + wv * DD + j] * ws[BCB_OFF + j];
                a = wred(a);
                if (lane == 0) ws[C3A + wv] = a;
            }
        } else {
            for (int job = wv; job < 5; job += 4) {
                const int so = (job == 0) ? UQWX_OFF
                             : (job == 1) ? W1_OFF
                             : A2_OFF + (job - 2) * DD;
                float a = 0.f;
                for (int j = lane; j < DD; j += 64)
                    a += ws[so + j] * ws[BCB_OFF + j];
                a = wred(a);
                if (lane == 0) {
                    if (job == 0)      ws[BU]  = a;
                    else if (job == 1) ws[BW1] = a;
                    else               ws[C3B + job - 2] = a;
                }
            }
        }
        return;
    }

    const int t = bi >> 4, g = bi & 15;
    const int sc = (lvl == 2) ? S2[t] : S3[t];
    const int mt = (lvl == 2) ? M2[t] : M3[t];
    const int dofs = (lvl == 2) ? T2[t] : T3[t];
    const float* M = (mt == 0) ? Wx : (mt == 1) ? (ws + X2_OFF) : (ws + C_OFF);

    for (int j = tid; j < 304; j += 256)
        sv[j] = (j < DD) ? ((sc >= 0) ? ws[sc + j] : Wd[(-sc - 1) * DD + j]) : 0.f;
    __syncthreads();

    const bool lo = (lane < 11);
    float4 a0{0,0,0,0}, a1{0,0,0,0};
    const int e0 = g * 19, e1 = min(e0 + 19, DD);
    for (int e = e0 + wv; e < e1; e += 4) {
        const float4* kr = (const float4*)(M + (size_t)e * DD);
        const float s = sv[e];
        FMA4(a0, s, kr[lane]);
        if (lo) { const float4 k1 = kr[64 + lane]; FMA4(a1, s, k1); }
    }
    float4* pr = (float4*)(buf + wv * 304);
    pr[lane] = a0;
    if (lo) pr[64 + lane] = a1;
    __syncthreads();
    for (int j = tid; j < DD; j += 256) {
        const float s = buf[j] + buf[304 + j] + buf[608 + j] + buf[912 + j];
        atomicAdd(ws + dofs + j, s);
    }
}

// ---------------------------------------------------------------------------
// build_tables: OCTET, 2 ROWS PER LANE. 782 blocks x 256 (3125 wave-tasks,
// 16 rows each). Octet o owns rows {task*16+o, task*16+o+8}; lane m (0..7)
// covers float4 chunks j = m+8t. Each V[j][k] LDS read now feeds TWO rows'
// FMAs -> 7.5 ds_read_b128 per row (half of r11). e-chunks use a rolling
// 3-deep prefetch (6 float4 live, ~80 VGPR -> ~6 waves/SIMD). V staged with
// stride 13 float4 (bank step 20 -> 8 octet phases on distinct banks).
// ---------------------------------------------------------------------------
#define VSTRIDE 13
__global__ __launch_bounds__(256) void build_tables(
    const float* __restrict__ emb, const float* __restrict__ wsr,
    float* __restrict__ tab)
{
    const int tid  = threadIdx.x;
    const int lane = tid & 63;
    const int m    = lane & 7;          // j-phase within octet
    const int oct  = lane >> 3;         // octet id 0..7

    __shared__ __align__(16) float4 Vl[76 * VSTRIDE];

    if (tid < 12) Vl[75 * VSTRIDE + tid] = float4{0, 0, 0, 0};
#define STAGE_V(k, off) \
    { const float4* src = (const float4*)(wsr + (off)); \
      for (int j = tid; j < 75; j += 256) Vl[j * VSTRIDE + (k)] = src[j]; }
    STAGE_V(0,  P1_OFF)
    STAGE_V(1,  P2_OFF)
    STAGE_V(2,  D1_OFF)
    STAGE_V(3,  D1_OFF + DD)
    STAGE_V(4,  D1_OFF + 2 * DD)
    STAGE_V(5,  D2_OFF)
    STAGE_V(6,  D2_OFF + DD)
    STAGE_V(7,  D2_OFF + 2 * DD)
    STAGE_V(8,  D3_OFF)
    STAGE_V(9,  D3_OFF + DD)
    STAGE_V(10, D3_OFF + 2 * DD)
    STAGE_V(11, U_OFF)
#undef STAGE_V
    __syncthreads();

    const int task = blockIdx.x * 4 + (tid >> 6);
    if (task >= VV / 16) return;           // 3125 tasks, exact (50000 = 3125*16)
    const int rowA = task * 16 + oct;
    const int rowB = rowA + 8;

    const float4* eA4 = (const float4*)(emb + (size_t)rowA * DD);
    const float4* eB4 = (const float4*)(emb + (size_t)rowB * DD);

    // rolling 3-deep prefetch of e-chunks (j = m + 8t)
    float4 eA0, eA1, eA2, eB0, eB1, eB2;
    {
        const int j0 = m, j1 = m + 8, j2 = m + 16;
        eA0 = eA4[j0]; eB0 = eB4[j0];              // j0 <= 7  < 75 always
        eA1 = eA4[j1]; eB1 = eB4[j1];              // j1 <= 15 < 75 always
        eA2 = eA4[j2]; eB2 = eB4[j2];              // j2 <= 23 < 75 always
    }

    float accA[12], accB[12];
    #pragma unroll
    for (int k = 0; k < 12; ++k) { accA[k] = 0.f; accB[k] = 0.f; }

    #pragma unroll
    for (int t = 0; t < 10; ++t) {
        // prefetch chunk t+3
        float4 nA{0, 0, 0, 0}, nB{0, 0, 0, 0};
        if (t < 7) {
            const int jn = m + 8 * (t + 3);
            if (jn < 75) { nA = eA4[jn]; nB = eB4[jn]; }
        }
        const int j = m + 8 * t;
        const float4* vp = &Vl[(j < 75 ? j : 75) * VSTRIDE];
        const float4 a = eA0, b = eB0;
        #pragma unroll
        for (int k = 0; k < 12; ++k) {
            const float4 w = vp[k];
            accA[k] += a.x * w.x + a.y * w.y + a.z * w.z + a.w * w.w;
            accB[k] += b.x * w.x + b.y * w.y + b.z * w.z + b.w * w.w;
        }
        eA0 = eA1; eA1 = eA2; eA2 = nA;
        eB0 = eB1; eB1 = eB2; eB2 = nB;
    }

    // octet reduction: xor1 + xor2 + xor4 (both rows)
    #pragma unroll
    for (int k = 0; k < 12; ++k) {
        accA[k] += __shfl_xor(accA[k], 1);
        accA[k] += __shfl_xor(accA[k], 2);
        accA[k] += __shfl_xor(accA[k], 4);
        accB[k] += __shfl_xor(accB[k], 1);
        accB[k] += __shfl_xor(accB[k], 2);
        accB[k] += __shfl_xor(accB[k], 4);
    }

    if (m == 0) {
        float4* tpA = (float4*)(tab + (size_t)rowA * 12);
        tpA[0] = float4{accA[0], accA[1], accA[2],  accA[3]};
        tpA[1] = float4{accA[4], accA[5], accA[6],  accA[7]};
        tpA[2] = float4{accA[8], accA[9], accA[10], accA[11]};
        float4* tpB = (float4*)(tab + (size_t)rowB * 12);
        tpB[0] = float4{accB[0], accB[1], accB[2],  accB[3]};
        tpB[1] = float4{accB[4], accB[5], accB[6],  accB[7]};
        tpB[2] = float4{accB[8], accB[9], accB[10], accB[11]};
    }
}
#undef VSTRIDE

// ---------------------------------------------------------------------------
// k_hops: 512 blocks x 512 threads (r3-proven).
// ---------------------------------------------------------------------------
__global__ __launch_bounds__(512) void k_hops(
    const int* __restrict__ text, const int* __restrict__ asp,
    const float* __restrict__ emb, float* __restrict__ out,
    const float* __restrict__ ws)
{
    const int b    = blockIdx.x;
    const int tid  = threadIdx.x;
    const int wv   = tid >> 6;
    const int lane = tid & 63;

    __shared__ __align__(16) float X0s[304];
    __shared__ float rlen[8];
    __shared__ float rp[8][6];
    __shared__ float qsv;

    const float ck  = ws[CK];
    const float cqs = ws[CQS];

    const int t = text[b * SS + tid];
    {
        const unsigned long long bal = __ballot(t != 0);
        if (lane == 0) rlen[wv] = (float)__popcll(bal);
    }
    const float4* tr = (const float4*)(ws + TAB_OFF + (size_t)t * 12);
    const float4 tA = tr[0];
    const float4 tB = tr[1];
    const float4 tC = tr[2];

    if (tid < DD) {
        float na = 0.f, a = 0.f;
        #pragma unroll
        for (int k = 0; k < 8; ++k) {
            const int idx = asp[b * 8 + k];
            na += (idx != 0) ? 1.0f : 0.0f;
            a += emb[(size_t)idx * DD + tid];
        }
        X0s[tid] = a / na;
    }
    __syncthreads();

    float lenf; int s0;
    {
        float l = 0.f;
        #pragma unroll
        for (int w = 0; w < 8; ++w) l += rlen[w];
        lenf = l; s0 = SS - (int)l;
    }
    const bool act = (tid >= s0);
    const float wg  = act ? (1.0f - (float)(tid - s0) / lenf) : 0.f;
    const float ksr = wg * tC.w + ck;

    float aw1 = 0.f, aw2 = 0.f, d12 = 0.f, o0 = 0.f, o1 = 0.f, o2 = 0.f;
    if (wv == 0) {
        float pq = 0.f, p1 = 0.f, p2 = 0.f, pd0 = 0.f, pd1 = 0.f, pd2 = 0.f;
        for (int j = lane; j < DD; j += 64) {
            const float x = X0s[j];
            pq  += x * ws[UQWX_OFF + j];
            p1  += x * ws[W1_OFF + j];
            p2  += x * ws[W2_OFF + j];
            pd0 += x * ws[D0_OFF + j];
            pd1 += x * ws[D0_OFF + DD + j];
            pd2 += x * ws[D0_OFF + 2 * DD + j];
        }
        pq = wred(pq); aw1 = wred(p1); aw2 = wred(p2);
        o0 = wred(pd0) + ws[C3A + 0] + ws[C3B + 0] + ws[C3C + 0];
        o1 = wred(pd1) + ws[C3A + 1] + ws[C3B + 1] + ws[C3C + 1];
        o2 = wred(pd2) + ws[C3A + 2] + ws[C3B + 2] + ws[C3C + 2];
        if (lane == 0) qsv = pq + cqs;
    }
    __syncthreads();

    const float bu = ws[BU], bw1 = ws[BW1];

    #pragma unroll
    for (int h = 0; h < 3; ++h) {
        const float qs = qsv;
        float p = 0.f;
        if (act) p = fast_exp_tanh(ksr + qs);
        const float pw = p * wg;
        float u0 = p, u1, u2, u3, u4 = 0.f, u5 = 0.f;
        if (h == 0)      { u1 = pw*tA.x; u2 = pw*tA.y; u3 = pw*tA.z; u4 = pw*tA.w; u5 = pw*tB.x; }
        else if (h == 1) { u1 = pw*tA.x; u2 = pw*tB.y; u3 = pw*tB.z; u4 = pw*tB.w; }
        else             { u1 = pw*tC.x; u2 = pw*tC.y; u3 = pw*tC.z; }
        u0 = wred(u0); u1 = wred(u1); u2 = wred(u2); u3 = wred(u3);
        if (h == 0) { u4 = wred(u4); u5 = wred(u5); }
        else if (h == 1) { u4 = wred(u4); }
        if (lane == 0) {
            rp[wv][0] = u0; rp[wv][1] = u1; rp[wv][2] = u2;
            rp[wv][3] = u3; rp[wv][4] = u4; rp[wv][5] = u5;
        }
        __syncthreads();
        if (wv == 0) {
            float s0_ = 0, s1_ = 0, s2_ = 0, s3_ = 0, s4_ = 0, s5_ = 0;
            #pragma unroll
            for (int w = 0; w < 8; ++w) {
                s0_ += rp[w][0]; s1_ += rp[w][1]; s2_ += rp[w][2];
                s3_ += rp[w][3]; s4_ += rp[w][4]; s5_ += rp[w][5];
            }
            const float sp  = s0_ + (float)s0 * fast_exp_tanh(ck + qs);
            const float isp = 1.0f / sp;
            if (h == 0) {
                d12 = isp * s2_;
                o0 += isp * s3_; o1 += isp * s4_; o2 += isp * s5_;
                if (lane == 0) qsv = isp * s1_ + aw1 + bu + cqs;
            } else if (h == 1) {
                o0 += isp * s2_; o1 += isp * s3_; o2 += isp * s4_;
                if (lane == 0) qsv = isp * s1_ + d12 + aw2 + bw1 + bu + cqs;
            } else if (lane == 0) {
                out[b * 3 + 0] = o0 + isp * s1_;
                out[b * 3 + 1] = o1 + isp * s2_;
                out[b * 3 + 2] = o2 + isp * s3_;
            }
        }
        if (h < 2) __syncthreads();
    }
}

extern "C" void kernel_launch(void* const* d_in, const int* in_sizes, int n_in,
                              void* d_out, int out_size, void* d_ws, size_t ws_size,
                              hipStream_t stream)
{
    const int*   text = (const int*)d_in[0];
    const int*   asp  = (const int*)d_in[1];
    const float* emb  = (const float*)d_in[2];
    const float* Wx   = (const float*)d_in[3];
    const float* bx   = (const float*)d_in[4];
    const float* Wk   = (const float*)d_in[5];
    const float* bk   = (const float*)d_in[6];
    const float* Wq   = (const float*)d_in[7];
    const float* bq   = (const float*)d_in[8];
    const float* wm   = (const float*)d_in[9];
    const float* Wp   = (const float*)d_in[10];
    const float* bp   = (const float*)d_in[11];
    const float* Wd   = (const float*)d_in[12];
    const float* bd   = (const float*)d_in[13];
    float* out = (float*)d_out;
    float* ws  = (float*)d_ws;

    pre1<<<205, 1024, 0, stream>>>(Wk, bk, Wq, bq, wm, Wp, bp, Wx, bx, Wd, bd, ws);
    plvl<<<11 * 16 + 1, 256, 0, stream>>>(Wx, Wd, ws, 2);
    plvl<<<9 * 16 + 1, 256, 0, stream>>>(Wx, Wd, ws, 3);
    const int nt16 = VV / 16;                     // 3125 wave-tasks
    build_tables<<<(nt16 + 3) / 4, 256, 0, stream>>>(emb, ws, ws + TAB_OFF);
    k_hops<<<512, 512, 0, stream>>>(text, asp, emb, out, ws);
}

// Round 14
// 163.317 us; speedup vs baseline: 1.0395x; 1.0395x over previous
//
#include <hip/hip_runtime.h>
#include <hip/hip_fp16.h>

#define DD 300
#define SS 512
#define VV 50000

// Workspace layout (float index):
#define CK       0
#define CQS      1
#define BU       2        // B·u
#define BW1      3        // B·w1
#define C3A      4        // (Wd@Wx)@B (3)
#define C3B      8        // (Wd@Wx^2)@B (3)
#define C3C      12       // Wd@B + bd (3)
#define U_OFF    16       // u_emb = Wk^T wk (300)
#define UQ_OFF   320      // uq = Wq^T wq (300)
#define UQWX_OFF 640      // u  = Wx^T uq (300)     [atomic, plvl2]
#define W1_OFF   960      // w1 = X2^T uq (300)     [atomic, plvl2]
#define W2_OFF   1280     // w2 = X2^T u (300)      [atomic, plvl3]
#define P1_OFF   1600     // p1 = C^T u             [atomic, plvl3]
#define P2_OFF   1920     // p2 = C^T w1            [atomic, plvl3]
#define D0_OFF   2240     // D0_r = Wx^T a2_r (3x300) [atomic, plvl3]
#define D1_OFF   3200     // D1_r = C^T a2_r        [atomic, plvl3]
#define D2_OFF   4160     // D2_r = C^T a1_r        [atomic, plvl2]
#define D3_OFF   5120     // D3_r = C^T d_r         [atomic, plvl2]
#define BCB_OFF  6080     // B = Wp@bk + bp + bx (300)
#define A1_OFF   6400     // a1_r = Wx^T d_r (3x300)
#define A2_OFF   7360     // a2_r = X2^T d_r (3x300) [atomic, plvl2]
#define TAB_OFF  16384    // tab[v][12]
#define X2_OFF   700000   // Wx@Wx row-major (90000)
#define C_OFF    800000   // Wp@Wk row-major (90000)

#define FMA4(acc, s, v) { acc.x += (s)*(v).x; acc.y += (s)*(v).y; \
                          acc.z += (s)*(v).z; acc.w += (s)*(v).w; }

__device__ __forceinline__ float fast_exp_tanh(float z) {
    const float t = __expf(2.0f * z);
    return __expf(1.0f - 2.0f / (t + 1.0f));
}

__device__ __forceinline__ float wred(float v) {
    #pragma unroll
    for (int off = 32; off; off >>= 1) v += __shfl_xor(v, off);
    return v;
}

// ---------------------------------------------------------------------------
// vcomb16: sOut[j] = sum_i sIn[i]*M[i][j], 1024 threads / 16 waves.
// ---------------------------------------------------------------------------
__device__ __forceinline__ void vcomb16(
    const float* __restrict__ M, const float* __restrict__ sIn,
    float* __restrict__ sOut, float* __restrict__ buf,
    const int tid, const int wv, const int lane)
{
    float4 a0{0,0,0,0}, a1{0,0,0,0};
    for (int e = wv; e < DD; e += 16) {
        const float4* kr = (const float4*)(M + (size_t)e * DD);
        const float s = sIn[e];
        FMA4(a0, s, kr[lane]);
        if (lane < 11) { const float4 k1 = kr[64 + lane]; FMA4(a1, s, k1); }
    }
    float4* pr = (float4*)(buf + wv * 304);
    pr[lane] = a0;
    if (lane < 11) pr[64 + lane] = a1;
    __syncthreads();
    if (tid < DD) {
        float s = 0.f;
        #pragma unroll
        for (int w = 0; w < 16; ++w) s += buf[w * 304 + tid];
        sOut[tid] = s;
    }
    __syncthreads();
}

// ---------------------------------------------------------------------------
// rowcomb3_16: sOut[r][:] = sum_i sIn[r][i]*M[i][:], 16 waves.
// ---------------------------------------------------------------------------
__device__ __forceinline__ void rowcomb3_16(
    const float* __restrict__ M, const float (*sIn)[304], float (*sOut)[304],
    float* __restrict__ buf, const int tid, const int wv, const int lane)
{
    float4 a00{0,0,0,0}, a01{0,0,0,0}, a10{0,0,0,0},
           a11{0,0,0,0}, a20{0,0,0,0}, a21{0,0,0,0};
    for (int e = wv; e < DD; e += 16) {
        const float4* kr = (const float4*)(M + (size_t)e * DD);
        const float4 k0 = kr[lane];
        const float p0 = sIn[0][e], p1 = sIn[1][e], p2 = sIn[2][e];
        FMA4(a00, p0, k0); FMA4(a10, p1, k0); FMA4(a20, p2, k0);
        if (lane < 11) {
            const float4 k1 = kr[64 + lane];
            FMA4(a01, p0, k1); FMA4(a11, p1, k1); FMA4(a21, p2, k1);
        }
    }
    float4* p0r = (float4*)(buf + (wv * 3 + 0) * 304);
    float4* p1r = (float4*)(buf + (wv * 3 + 1) * 304);
    float4* p2r = (float4*)(buf + (wv * 3 + 2) * 304);
    p0r[lane] = a00; p1r[lane] = a10; p2r[lane] = a20;
    if (lane < 11) { p0r[64+lane] = a01; p1r[64+lane] = a11; p2r[64+lane] = a21; }
    __syncthreads();
    if (tid < DD) {
        #pragma unroll
        for (int r = 0; r < 3; ++r) {
            float s = 0.f;
            for (int w = 0; w < 16; ++w) s += buf[(w * 3 + r) * 304 + tid];
            sOut[r][tid] = s;
        }
    }
    __syncthreads();
}

// ---------------------------------------------------------------------------
// pre1: 205 blocks x 1024.
//   0..99  : C = Wp@Wk rows.  100..199: X2 = Wx@Wx rows.
//   200: ue = Wk^T wk ; ck.   201: uq = Wq^T wq ; cqs.
//   202: B = Wp@bk+bp+bx ; c3c_r = Wd_r·B + bd_r.
//   203: a1_r = Wx^T Wd_r.    204: zero all atomic targets of plvl2/plvl3.
// ---------------------------------------------------------------------------
__global__ __launch_bounds__(1024) void pre1(
    const float* __restrict__ Wk, const float* __restrict__ bk,
    const float* __restrict__ Wq, const float* __restrict__ bq,
    const float* __restrict__ w_mlp,
    const float* __restrict__ Wp, const float* __restrict__ bp,
    const float* __restrict__ Wx, const float* __restrict__ bx,
    const float* __restrict__ Wd, const float* __restrict__ bd,
    float* __restrict__ ws)
{
    const int blk  = blockIdx.x;
    const int tid  = threadIdx.x;
    const int wv   = tid >> 6;
    const int lane = tid & 63;
    __shared__ __align__(16) float buf[16 * 304 * 3];
    __shared__ __align__(16) float v0[304], v1[304], vB[304];
    __shared__ __align__(16) float m0[3][304], mW[3][304];
    __shared__ float red[16];

    if (blk < 200) {
        const bool isC = (blk < 100);
        const int i0 = (isC ? blk : blk - 100) * 3;
        const float* Arows = isC ? Wp : Wx;
        const float* Mrows = isC ? Wk : Wx;
        const int outoff = isC ? C_OFF : X2_OFF;

        for (int r = tid; r < 3 * DD; r += 1024)
            mW[r / DD][r % DD] = Arows[i0 * DD + r];
        __syncthreads();

        float4 a00{0,0,0,0}, a01{0,0,0,0}, a10{0,0,0,0},
               a11{0,0,0,0}, a20{0,0,0,0}, a21{0,0,0,0};
        for (int e = wv; e < DD; e += 16) {
            const float4* kr = (const float4*)(Mrows + (size_t)e * DD);
            const float4 k0 = kr[lane];
            const float p0 = mW[0][e], p1 = mW[1][e], p2 = mW[2][e];
            FMA4(a00, p0, k0); FMA4(a10, p1, k0); FMA4(a20, p2, k0);
            if (lane < 11) {
                const float4 k1 = kr[64 + lane];
                FMA4(a01, p0, k1); FMA4(a11, p1, k1); FMA4(a21, p2, k1);
            }
        }
        float4* p0r = (float4*)(buf + (wv * 3 + 0) * 304);
        float4* p1r = (float4*)(buf + (wv * 3 + 1) * 304);
        float4* p2r = (float4*)(buf + (wv * 3 + 2) * 304);
        p0r[lane] = a00; p1r[lane] = a10; p2r[lane] = a20;
        if (lane < 11) { p0r[64+lane] = a01; p1r[64+lane] = a11; p2r[64+lane] = a21; }
        __syncthreads();
        if (tid < DD) {
            #pragma unroll
            for (int r = 0; r < 3; ++r) {
                float s = 0.f;
                for (int w = 0; w < 16; ++w) s += buf[(w * 3 + r) * 304 + tid];
                ws[outoff + (size_t)(i0 + r) * DD + tid] = s;
            }
        }
        return;
    }

    if (blk == 200) {                       // ue + ck
        if (tid < DD) v0[tid] = w_mlp[tid];
        __syncthreads();
        vcomb16(Wk, v0, v1, buf, tid, wv, lane);
        if (tid < DD) ws[U_OFF + tid] = v1[tid];
        float p = (tid < DD) ? v0[tid] * bk[tid] : 0.f;
        p = wred(p);
        if (lane == 0) red[wv] = p;
        __syncthreads();
        if (tid == 0) {
            float s = 0.f;
            for (int w = 0; w < 16; ++w) s += red[w];
            ws[CK] = s;
        }
        return;
    }

    if (blk == 201) {                       // uq + cqs
        if (tid < DD) v0[tid] = w_mlp[DD + tid];
        __syncthreads();
        vcomb16(Wq, v0, v1, buf, tid, wv, lane);
        if (tid < DD) ws[UQ_OFF + tid] = v1[tid];
        float p = (tid < DD) ? (v0[tid] * bq[tid] + v1[tid] * bx[tid]) : 0.f;
        p = wred(p);
        if (lane == 0) red[wv] = p;
        __syncthreads();
        if (tid == 0) {
            float s = 0.f;
            for (int w = 0; w < 16; ++w) s += red[w];
            ws[CQS] = s;
        }
        return;
    }

    if (blk == 202) {                       // B + c3c
        if (tid < DD) v0[tid] = bk[tid];
        __syncthreads();
        {
            const float4* b4 = (const float4*)v0;
            const float4 k0 = b4[lane];
            const float4 k1 = (lane < 11) ? b4[64 + lane] : float4{0, 0, 0, 0};
            for (int i2 = wv; i2 < DD; i2 += 16) {
                const float4* wr = (const float4*)(Wp + (size_t)i2 * DD);
                const float4 w0 = wr[lane];
                float a = w0.x * k0.x + w0.y * k0.y + w0.z * k0.z + w0.w * k0.w;
                if (lane < 11) {
                    const float4 w1 = wr[64 + lane];
                    a += w1.x * k1.x + w1.y * k1.y + w1.z * k1.z + w1.w * k1.w;
                }
                a = wred(a);
                if (lane == 0) { vB[i2] = a + bp[i2] + bx[i2]; }
            }
        }
        __syncthreads();
        if (tid < DD) ws[BCB_OFF + tid] = vB[tid];
        if (wv < 3) {                       // c3c_r = Wd_r·B + bd_r
            float a = 0.f;
            for (int j = lane; j < DD; j += 64) a += Wd[wv * DD + j] * vB[j];
            a = wred(a);
            if (lane == 0) ws[C3C + wv] = a + bd[wv];
        }
        return;
    }

    if (blk == 203) {                       // a1_r = Wd_r @ Wx
        for (int r = tid; r < 3 * DD; r += 1024) mW[r / DD][r % DD] = Wd[r];
        __syncthreads();
        rowcomb3_16(Wx, mW, m0, buf, tid, wv, lane);
        for (int r = tid; r < 3 * DD; r += 1024)
            ws[A1_OFF + (r / DD) * DD + (r % DD)] = m0[r / DD][r % DD];
        return;
    }

    {   // blk 204: zero atomic targets
#define ZZ(off, len) for (int j = tid; j < (len); j += 1024) ws[(off) + j] = 0.f;
        ZZ(UQWX_OFF, 300) ZZ(W1_OFF, 300) ZZ(W2_OFF, 300)
        ZZ(P1_OFF, 300)   ZZ(P2_OFF, 300)
        ZZ(A2_OFF, 900)   ZZ(D0_OFF, 900) ZZ(D1_OFF, 900)
        ZZ(D2_OFF, 900)   ZZ(D3_OFF, 900)
#undef ZZ
    }
}

// ---------------------------------------------------------------------------
// plvl: level 2/3 products, each split 16-way over the reduction dim with
// atomicAdd accumulation (targets zeroed in pre1 blk204). 256 threads.
// Last block computes the level's scalars.
// ---------------------------------------------------------------------------
__global__ __launch_bounds__(256) void plvl(
    const float* __restrict__ Wx, const float* __restrict__ Wd,
    float* __restrict__ ws, const int lvl)
{
    const int S2[11] = {UQ_OFF, UQ_OFF, -1, -2, -3, -1, -2, -3,
                        A1_OFF, A1_OFF + 300, A1_OFF + 600};
    const int M2[11] = {0, 1, 1, 1, 1, 2, 2, 2, 2, 2, 2};
    const int T2[11] = {UQWX_OFF, W1_OFF, A2_OFF, A2_OFF + 300, A2_OFF + 600,
                        D3_OFF, D3_OFF + 300, D3_OFF + 600,
                        D2_OFF, D2_OFF + 300, D2_OFF + 600};
    const int S3[9]  = {UQWX_OFF, UQWX_OFF, W1_OFF,
                        A2_OFF, A2_OFF + 300, A2_OFF + 600,
                        A2_OFF, A2_OFF + 300, A2_OFF + 600};
    const int M3[9]  = {1, 2, 2, 2, 2, 2, 0, 0, 0};
    const int T3[9]  = {W2_OFF, P1_OFF, P2_OFF,
                        D1_OFF, D1_OFF + 300, D1_OFF + 600,
                        D0_OFF, D0_OFF + 300, D0_OFF + 600};
    const int nt = (lvl == 2) ? 11 : 9;

    const int tid  = threadIdx.x;
    const int lane = tid & 63;
    const int wv   = tid >> 6;
    const int bi   = blockIdx.x;

    __shared__ __align__(16) float sv[304];
    __shared__ __align__(16) float buf[4 * 304];

    if (bi >= nt * 16) {                    // scalar block
        if (lvl == 2) {
            if (wv < 3) {                   // c3a_r = a1_r·B
                float a = 0.f;
                for (int j = lane; j < DD; j += 64)
                    a += ws[A1_OFF + wv * DD + j] * ws[BCB_OFF + j];
                a = wred(a);
                if (lane == 0) ws[C3A + wv] = a;
            }
        } else {
            for (int job = wv; job < 5; job += 4) {
                const int so = (job == 0) ? UQWX_OFF
                             : (job == 1) ? W1_OFF
                             : A2_OFF + (job - 2) * DD;
                float a = 0.f;
                for (int j = lane; j < DD; j += 64)
                    a += ws[so + j] * ws[BCB_OFF + j];
                a = wred(a);
                if (lane == 0) {
                    if (job == 0)      ws[BU]  = a;
                    else if (job == 1) ws[BW1] = a;
                    else               ws[C3B + job - 2] = a;
                }
            }
        }
        return;
    }

    const int t = bi >> 4, g = bi & 15;
    const int sc = (lvl == 2) ? S2[t] : S3[t];
    const int mt = (lvl == 2) ? M2[t] : M3[t];
    const int dofs = (lvl == 2) ? T2[t] : T3[t];
    const float* M = (mt == 0) ? Wx : (mt == 1) ? (ws + X2_OFF) : (ws + C_OFF);

    for (int j = tid; j < 304; j += 256)
        sv[j] = (j < DD) ? ((sc >= 0) ? ws[sc + j] : Wd[(-sc - 1) * DD + j]) : 0.f;
    __syncthreads();

    const bool lo = (lane < 11);
    float4 a0{0,0,0,0}, a1{0,0,0,0};
    const int e0 = g * 19, e1 = min(e0 + 19, DD);
    for (int e = e0 + wv; e < e1; e += 4) {
        const float4* kr = (const float4*)(M + (size_t)e * DD);
        const float s = sv[e];
        FMA4(a0, s, kr[lane]);
        if (lo) { const float4 k1 = kr[64 + lane]; FMA4(a1, s, k1); }
    }
    float4* pr = (float4*)(buf + wv * 304);
    pr[lane] = a0;
    if (lo) pr[64 + lane] = a1;
    __syncthreads();
    for (int j = tid; j < DD; j += 256) {
        const float s = buf[j] + buf[304 + j] + buf[608 + j] + buf[912 + j];
        atomicAdd(ws + dofs + j, s);
    }
}

// ---------------------------------------------------------------------------
// build_tables: OCTET-per-row GEMM (r11-measured best: 163.6 us total).
// 1563 blocks x 256 (6250 wave-tasks). Each wave handles 8 rows; octet o
// owns row task*8+o; lane m (0..7) covers float4 chunks j = m+8t (128B
// contiguous per octet per step). V staged in LDS with stride 13 float4
// (bank step 20 %32 -> 8 octet phases on distinct banks). 10 e-chunks
// preloaded (~80 VGPR -> ~6 waves/SIMD, ~24 waves/CU). Reduction = 3
// shuffle stages per 8 rows.
// ---------------------------------------------------------------------------
#define VSTRIDE 13
__global__ __launch_bounds__(256) void build_tables(
    const float* __restrict__ emb, const float* __restrict__ wsr,
    float* __restrict__ tab)
{
    const int tid  = threadIdx.x;
    const int lane = tid & 63;
    const int m    = lane & 7;          // j-phase within octet
    const int oct  = lane >> 3;         // octet id 0..7

    __shared__ __align__(16) float4 Vl[76 * VSTRIDE];

    if (tid < 12) Vl[75 * VSTRIDE + tid] = float4{0, 0, 0, 0};
#define STAGE_V(k, off) \
    { const float4* src = (const float4*)(wsr + (off)); \
      for (int j = tid; j < 75; j += 256) Vl[j * VSTRIDE + (k)] = src[j]; }
    STAGE_V(0,  P1_OFF)
    STAGE_V(1,  P2_OFF)
    STAGE_V(2,  D1_OFF)
    STAGE_V(3,  D1_OFF + DD)
    STAGE_V(4,  D1_OFF + 2 * DD)
    STAGE_V(5,  D2_OFF)
    STAGE_V(6,  D2_OFF + DD)
    STAGE_V(7,  D2_OFF + 2 * DD)
    STAGE_V(8,  D3_OFF)
    STAGE_V(9,  D3_OFF + DD)
    STAGE_V(10, D3_OFF + 2 * DD)
    STAGE_V(11, U_OFF)
#undef STAGE_V
    __syncthreads();

    const int task = blockIdx.x * 4 + (tid >> 6);
    if (task >= (VV + 7) / 8) return;
    const int row = task * 8 + oct;

    const float4* er4 = (const float4*)(emb + (size_t)row * DD);

    // preload 10 e-chunks (j = m + 8t); invalid tail chunk -> 0
    float4 e[10];
    #pragma unroll
    for (int t = 0; t < 10; ++t) {
        const int j = m + 8 * t;
        if (j < 75) e[t] = er4[j];
        else        e[t] = float4{0, 0, 0, 0};
    }

    float acc[12];
    #pragma unroll
    for (int k = 0; k < 12; ++k) acc[k] = 0.f;

    #pragma unroll
    for (int t = 0; t < 10; ++t) {
        const int j = m + 8 * t;
        const float4* vp = &Vl[(j < 75 ? j : 75) * VSTRIDE];
        const float4 ev = e[t];
        #pragma unroll
        for (int k = 0; k < 12; ++k) {
            const float4 w = vp[k];
            acc[k] += ev.x * w.x + ev.y * w.y + ev.z * w.z + ev.w * w.w;
        }
    }

    // octet reduction: xor1 + xor2 + xor4
    #pragma unroll
    for (int k = 0; k < 12; ++k) {
        acc[k] += __shfl_xor(acc[k], 1);
        acc[k] += __shfl_xor(acc[k], 2);
        acc[k] += __shfl_xor(acc[k], 4);
    }

    if (m == 0) {
        float4* tp = (float4*)(tab + (size_t)row * 12);
        tp[0] = float4{acc[0], acc[1], acc[2],  acc[3]};
        tp[1] = float4{acc[4], acc[5], acc[6],  acc[7]};
        tp[2] = float4{acc[8], acc[9], acc[10], acc[11]};
    }
}
#undef VSTRIDE

// ---------------------------------------------------------------------------
// k_hops: 512 blocks x 512 threads (r3-proven).
// ---------------------------------------------------------------------------
__global__ __launch_bounds__(512) void k_hops(
    const int* __restrict__ text, const int* __restrict__ asp,
    const float* __restrict__ emb, float* __restrict__ out,
    const float* __restrict__ ws)
{
    const int b    = blockIdx.x;
    const int tid  = threadIdx.x;
    const int wv   = tid >> 6;
    const int lane = tid & 63;

    __shared__ __align__(16) float X0s[304];
    __shared__ float rlen[8];
    __shared__ float rp[8][6];
    __shared__ float qsv;

    const float ck  = ws[CK];
    const float cqs = ws[CQS];

    const int t = text[b * SS + tid];
    {
        const unsigned long long bal = __ballot(t != 0);
        if (lane == 0) rlen[wv] = (float)__popcll(bal);
    }
    const float4* tr = (const float4*)(ws + TAB_OFF + (size_t)t * 12);
    const float4 tA = tr[0];
    const float4 tB = tr[1];
    const float4 tC = tr[2];

    if (tid < DD) {
        float na = 0.f, a = 0.f;
        #pragma unroll
        for (int k = 0; k < 8; ++k) {
            const int idx = asp[b * 8 + k];
            na += (idx != 0) ? 1.0f : 0.0f;
            a += emb[(size_t)idx * DD + tid];
        }
        X0s[tid] = a / na;
    }
    __syncthreads();

    float lenf; int s0;
    {
        float l = 0.f;
        #pragma unroll
        for (int w = 0; w < 8; ++w) l += rlen[w];
        lenf = l; s0 = SS - (int)l;
    }
    const bool act = (tid >= s0);
    const float wg  = act ? (1.0f - (float)(tid - s0) / lenf) : 0.f;
    const float ksr = wg * tC.w + ck;

    float aw1 = 0.f, aw2 = 0.f, d12 = 0.f, o0 = 0.f, o1 = 0.f, o2 = 0.f;
    if (wv == 0) {
        float pq = 0.f, p1 = 0.f, p2 = 0.f, pd0 = 0.f, pd1 = 0.f, pd2 = 0.f;
        for (int j = lane; j < DD; j += 64) {
            const float x = X0s[j];
            pq  += x * ws[UQWX_OFF + j];
            p1  += x * ws[W1_OFF + j];
            p2  += x * ws[W2_OFF + j];
            pd0 += x * ws[D0_OFF + j];
            pd1 += x * ws[D0_OFF + DD + j];
            pd2 += x * ws[D0_OFF + 2 * DD + j];
        }
        pq = wred(pq); aw1 = wred(p1); aw2 = wred(p2);
        o0 = wred(pd0) + ws[C3A + 0] + ws[C3B + 0] + ws[C3C + 0];
        o1 = wred(pd1) + ws[C3A + 1] + ws[C3B + 1] + ws[C3C + 1];
        o2 = wred(pd2) + ws[C3A + 2] + ws[C3B + 2] + ws[C3C + 2];
        if (lane == 0) qsv = pq + cqs;
    }
    __syncthreads();

    const float bu = ws[BU], bw1 = ws[BW1];

    #pragma unroll
    for (int h = 0; h < 3; ++h) {
        const float qs = qsv;
        float p = 0.f;
        if (act) p = fast_exp_tanh(ksr + qs);
        const float pw = p * wg;
        float u0 = p, u1, u2, u3, u4 = 0.f, u5 = 0.f;
        if (h == 0)      { u1 = pw*tA.x; u2 = pw*tA.y; u3 = pw*tA.z; u4 = pw*tA.w; u5 = pw*tB.x; }
        else if (h == 1) { u1 = pw*tA.x; u2 = pw*tB.y; u3 = pw*tB.z; u4 = pw*tB.w; }
        else             { u1 = pw*tC.x; u2 = pw*tC.y; u3 = pw*tC.z; }
        u0 = wred(u0); u1 = wred(u1); u2 = wred(u2); u3 = wred(u3);
        if (h == 0) { u4 = wred(u4); u5 = wred(u5); }
        else if (h == 1) { u4 = wred(u4); }
        if (lane == 0) {
            rp[wv][0] = u0; rp[wv][1] = u1; rp[wv][2] = u2;
            rp[wv][3] = u3; rp[wv][4] = u4; rp[wv][5] = u5;
        }
        __syncthreads();
        if (wv == 0) {
            float s0_ = 0, s1_ = 0, s2_ = 0, s3_ = 0, s4_ = 0, s5_ = 0;
            #pragma unroll
            for (int w = 0; w < 8; ++w) {
                s0_ += rp[w][0]; s1_ += rp[w][1]; s2_ += rp[w][2];
                s3_ += rp[w][3]; s4_ += rp[w][4]; s5_ += rp[w][5];
            }
            const float sp  = s0_ + (float)s0 * fast_exp_tanh(ck + qs);
            const float isp = 1.0f / sp;
            if (h == 0) {
                d12 = isp * s2_;
                o0 += isp * s3_; o1 += isp * s4_; o2 += isp * s5_;
                if (lane == 0) qsv = isp * s1_ + aw1 + bu + cqs;
            } else if (h == 1) {
                o0 += isp * s2_; o1 += isp * s3_; o2 += isp * s4_;
                if (lane == 0) qsv = isp * s1_ + d12 + aw2 + bw1 + bu + cqs;
            } else if (lane == 0) {
                out[b * 3 + 0] = o0 + isp * s1_;
                out[b * 3 + 1] = o1 + isp * s2_;
                out[b * 3 + 2] = o2 + isp * s3_;
            }
        }
        if (h < 2) __syncthreads();
    }
}

extern "C" void kernel_launch(void* const* d_in, const int* in_sizes, int n_in,
                              void* d_out, int out_size, void* d_ws, size_t ws_size,
                              hipStream_t stream)
{
    const int*   text = (const int*)d_in[0];
    const int*   asp  = (const int*)d_in[1];
    const float* emb  = (const float*)d_in[2];
    const float* Wx   = (const float*)d_in[3];
    const float* bx   = (const float*)d_in[4];
    const float* Wk   = (const float*)d_in[5];
    const float* bk   = (const float*)d_in[6];
    const float* Wq   = (const float*)d_in[7];
    const float* bq   = (const float*)d_in[8];
    const float* wm   = (const float*)d_in[9];
    const float* Wp   = (const float*)d_in[10];
    const float* bp   = (const float*)d_in[11];
    const float* Wd   = (const float*)d_in[12];
    const float* bd   = (const float*)d_in[13];
    float* out = (float*)d_out;
    float* ws  = (float*)d_ws;

    pre1<<<205, 1024, 0, stream>>>(Wk, bk, Wq, bq, wm, Wp, bp, Wx, bx, Wd, bd, ws);
    plvl<<<11 * 16 + 1, 256, 0, stream>>>(Wx, Wd, ws, 2);
    plvl<<<9 * 16 + 1, 256, 0, stream>>>(Wx, Wd, ws, 3);
    const int nt8 = (VV + 7) / 8;                 // 6250 wave-tasks
    build_tables<<<(nt8 + 3) / 4, 256, 0, stream>>>(emb, ws, ws + TAB_OFF);
    k_hops<<<512, 512, 0, stream>>>(text, asp, emb, out, ws);
}